// Round 5
// baseline (634.026 us; speedup 1.0000x reference)
//
#include <hip/hip_runtime.h>
#include <hip/hip_cooperative_groups.h>
#include <stdint.h>

namespace cg = cooperative_groups;

// Problem constants
#define N_NODES 25000
#define N_EDGES 400000
// N=2, IN_DIM=64, HEADS=4, HEAD_DIM=16; feature rows = (idx*2+n)*64 floats

typedef __attribute__((ext_vector_type(8))) short short8;   // 8 bf16 = 4 VGPRs
typedef __attribute__((ext_vector_type(4))) float f32x4;    // MFMA accum

#define MFMA16(a, b, c) __builtin_amdgcn_mfma_f32_16x16x32_bf16((a), (b), (c), 0, 0, 0)

// fp32 -> bf16, round-to-nearest-even (weights / q path)
__device__ __forceinline__ short bf16r(float x) {
    unsigned u = __float_as_uint(x);
    u += 0x7FFFu + ((u >> 16) & 1u);
    return (short)(u >> 16);
}
// fp32 -> bf16, round-half-up (hot edge path)
__device__ __forceinline__ short bfr(float x) {
    return (short)((__float_as_uint(x) + 0x8000u) >> 16);
}

// Sum over each 16-lane group via DPP butterfly (pure VALU).
#define DPP_ADD(x, ctrl) \
    ((x) + __int_as_float(__builtin_amdgcn_update_dpp(0, __float_as_int(x), (ctrl), 0xF, 0xF, true)))
__device__ __forceinline__ float red16(float x) {
    x = DPP_ADD(x, 0xB1);    // quad_perm [1,0,3,2]
    x = DPP_ADD(x, 0x4E);    // quad_perm [2,3,0,1]
    x = DPP_ADD(x, 0x141);   // row_half_mirror
    x = DPP_ADD(x, 0x140);   // row_mirror
    return x;
}

// B fragment for cols [colbase, colbase+16) of [64 x 64] row-major fp32 W.
__device__ __forceinline__ short8 load_bfrag(const float* __restrict__ W,
                                             int colbase, int lane, int khalf) {
    const int n = colbase + (lane & 15);
    const int k0 = khalf * 32 + ((lane >> 4) << 3);
    short8 f;
    #pragma unroll
    for (int j = 0; j < 8; ++j) f[j] = bf16r(W[(k0 + j) * 64 + n]);
    return f;
}

// A fragment from LDS tile (16 rows padded to 72 shorts = 144 B).
__device__ __forceinline__ short8 afrag(const short* S, int lane, int khalf) {
    return *(const short8*)&S[(lane & 15) * 72 + khalf * 32 + ((lane >> 4) << 3)];
}

// ======================= fused cooperative kernel =======================
__global__ __launch_bounds__(256, 2) void fused_kernel(
    const float* __restrict__ h, const float* __restrict__ e,
    const float* __restrict__ Wq, const float* __restrict__ Wk,
    const float* __restrict__ Wv, const float* __restrict__ Wr,
    const int* __restrict__ src, const int* __restrict__ dst,
    float* __restrict__ Q, int* __restrict__ counts, int* __restrict__ offsets,
    int* __restrict__ cursor, int* __restrict__ perm, int* __restrict__ srcs,
    short8* __restrict__ fw, int* __restrict__ partials, float* __restrict__ out)
{
    cg::grid_group grid = cg::this_grid();
    __shared__ __align__(16) char smem[18432];   // union: q-tile / scan / edge slabs
    const int t = threadIdx.x, b = blockIdx.x, G = gridDim.x;
    const int lane = t & 63, w = t >> 6;
    const int ln = lane & 15, lq = lane >> 4;

    // ---------- P0: zero counts ----------
    for (int i = b * 256 + t; i < N_NODES; i += G * 256) counts[i] = 0;
    grid.sync();

    // ---------- P1: hist atomics + Q=h@Wq MFMA + fw prep (independent) ----------
    for (int i = b * 256 + t; i < N_EDGES; i += G * 256) atomicAdd(&counts[dst[i]], 1);
    {
        short* sH = (short*)smem;                 // 64*72 shorts = 9216 B
        const int wcol = w << 4;
        const short8 wb0 = load_bfrag(Wq, wcol, lane, 0);
        const short8 wb1 = load_bfrag(Wq, wcol, lane, 1);
        const int r = t >> 2, c4 = (t & 3) << 4;  // staging role
        for (int tile = b; tile < 782; tile += G) {
            const int base = tile * 64;
            __syncthreads();                      // protect sH reuse
            {
                int row = base + r; if (row > 49999) row = 49999;
                const float4* p = (const float4*)&h[row * 64 + c4];
                short tmp[16];
                #pragma unroll
                for (int i = 0; i < 4; ++i) {
                    float4 x = p[i];
                    tmp[4*i+0] = bf16r(x.x); tmp[4*i+1] = bf16r(x.y);
                    tmp[4*i+2] = bf16r(x.z); tmp[4*i+3] = bf16r(x.w);
                }
                *(short8*)&sH[r * 72 + c4]     = *(short8*)&tmp[0];
                *(short8*)&sH[r * 72 + c4 + 8] = *(short8*)&tmp[8];
            }
            __syncthreads();
            #pragma unroll
            for (int m = 0; m < 4; ++m) {
                const short* Sm = &sH[(m << 4) * 72];
                short8 a0 = afrag(Sm, lane, 0);
                short8 a1 = afrag(Sm, lane, 1);
                f32x4 acc = {0.f, 0.f, 0.f, 0.f};
                acc = MFMA16(a0, wb0, acc);
                acc = MFMA16(a1, wb1, acc);
                #pragma unroll
                for (int reg = 0; reg < 4; ++reg) {
                    const int row = base + (m << 4) + (lq << 2) + reg;
                    if (row < 50000) Q[row * 64 + wcol + ln] = acc[reg];
                }
            }
        }
        if (b == 0) {
            fw[(w * 6 + 0) * 64 + lane] = load_bfrag(Wk, wcol, lane, 0);
            fw[(w * 6 + 1) * 64 + lane] = load_bfrag(Wk, wcol, lane, 1);
            fw[(w * 6 + 2) * 64 + lane] = load_bfrag(Wv, wcol, lane, 0);
            fw[(w * 6 + 3) * 64 + lane] = load_bfrag(Wv, wcol, lane, 1);
            fw[(w * 6 + 4) * 64 + lane] = load_bfrag(Wr, wcol, lane, 0);
            fw[(w * 6 + 5) * 64 + lane] = load_bfrag(Wr, wcol, lane, 1);
        }
    }
    grid.sync();

    // ---------- P2a: block partial sums + in-block inclusive scan ----------
    const int C = (N_NODES + G - 1) / G;          // per-block range; C<=256 for G>=98
    const int r0 = b * C;
    int* sI = (int*)smem;
    int cnt_t = 0;
    if (t < C && (r0 + t) < N_NODES) cnt_t = counts[r0 + t];
    __syncthreads();                              // smem phase transition
    sI[t] = cnt_t;
    __syncthreads();
    #pragma unroll
    for (int d = 1; d < 256; d <<= 1) {           // Hillis-Steele inclusive
        const int add = (t >= d) ? sI[t - d] : 0;
        __syncthreads();
        sI[t] += add;
        __syncthreads();
    }
    const int incl  = sI[t];
    const int total = sI[255];
    if (t == 0) partials[b] = total;
    grid.sync();

    // ---------- P2b: every block computes its prefix; write offsets/cursor ----------
    int pre = 0;
    for (int j = t; j < b; j += 256) pre += partials[j];
    __syncthreads();
    sI[t] = pre;
    __syncthreads();
    #pragma unroll
    for (int d = 128; d > 0; d >>= 1) {
        if (t < d) sI[t] += sI[t + d];
        __syncthreads();
    }
    pre = sI[0];
    if (t < C && (r0 + t) < N_NODES) {
        const int excl = pre + incl - cnt_t;
        offsets[r0 + t] = excl;
        cursor[r0 + t]  = excl;
    }
    if (b == 0 && t == 0) offsets[N_NODES] = N_EDGES;
    grid.sync();

    // ---------- P3: scatter (order within a node irrelevant for max) ----------
    for (int i = b * 256 + t; i < N_EDGES; i += G * 256) {
        const int d = dst[i];
        const int pos = atomicAdd(&cursor[d], 1);
        perm[pos] = i;
        srcs[pos] = src[i];
    }
    grid.sync();

    // ---------- P4: edge phase, one wave per node, persistent grid-stride ----------
    short* SD = (short*)smem + w * 2304;          // per-wave slabs
    short* SE = SD + 1152;

    short8 bK0[4], bK1[4], bV0[4], bV1[4], bR0[4], bR1[4];
    #pragma unroll
    for (int hd = 0; hd < 4; ++hd) {
        bK0[hd] = fw[(hd * 6 + 0) * 64 + lane];
        bK1[hd] = fw[(hd * 6 + 1) * 64 + lane];
        bV0[hd] = fw[(hd * 6 + 2) * 64 + lane];
        bV1[hd] = fw[(hd * 6 + 3) * 64 + lane];
        bR0[hd] = fw[(hd * 6 + 4) * 64 + lane];
        bR1[hd] = fw[(hd * 6 + 5) * 64 + lane];
    }

    const int r  = lane >> 2;                     // staging A-row
    const int cq = (lane & 3) << 4;
    const int n_r = r & 1;
    const float NEG_INF = __uint_as_float(0xFF800000u);

    for (int v = (b << 2) + w; v < N_NODES; v += (G << 2)) {
        const int off0 = offsets[v];
        const int off1 = offsets[v + 1];
        const int deg  = off1 - off0;

        if (deg == 0) {                           // zero in-degree -> 0
            out[(v << 7) + lane]      = 0.0f;
            out[(v << 7) + 64 + lane] = 0.0f;
            continue;
        }

        float q0[4], q1[4], qn0[4], qn1[4];
        #pragma unroll
        for (int hd = 0; hd < 4; ++hd) {
            q0[hd] = Q[(v << 7) + (hd << 4) + ln];
            q1[hd] = Q[(v << 7) + 64 + (hd << 4) + ln];
            qn0[hd] = sqrtf(red16(q0[hd] * q0[hd]));
            qn1[hd] = sqrtf(red16(q1[hd] * q1[hd]));
        }

        float4 xd[4];
        {
            const float4* pd = (const float4*)&h[(((v << 1) + n_r) << 6) + cq];
            xd[0] = pd[0]; xd[1] = pd[1]; xd[2] = pd[2]; xd[3] = pd[3];
        }

        float rm0[4] = {NEG_INF, NEG_INF, NEG_INF, NEG_INF};
        float rm1[4] = {NEG_INF, NEG_INF, NEG_INF, NEG_INF};

        const int nch = (deg + 7) >> 3;
        for (int c = 0; c < nch; ++c) {
            int eidx = off0 + (c << 3) + (r >> 1);
            if (eidx > off1 - 1) eidx = off1 - 1;         // clamp (loads only)
            const int ed = perm[eidx];
            const int s  = srcs[eidx];
            const float4* ps = (const float4*)&h[(((s  << 1) + n_r) << 6) + cq];
            const float4* pe = (const float4*)&e[(((ed << 1) + n_r) << 6) + cq];

            short tmd[16], tme[16];
            #pragma unroll
            for (int i = 0; i < 4; ++i) {
                const float4 xs = ps[i], xe = pe[i];
                tmd[4*i+0] = bfr(fmaxf(xs.x - xd[i].x, 0.f));
                tmd[4*i+1] = bfr(fmaxf(xs.y - xd[i].y, 0.f));
                tmd[4*i+2] = bfr(fmaxf(xs.z - xd[i].z, 0.f));
                tmd[4*i+3] = bfr(fmaxf(xs.w - xd[i].w, 0.f));
                tme[4*i+0] = bfr(xe.x); tme[4*i+1] = bfr(xe.y);
                tme[4*i+2] = bfr(xe.z); tme[4*i+3] = bfr(xe.w);
            }
            *(short8*)&SD[r * 72 + cq]     = *(short8*)&tmd[0];
            *(short8*)&SD[r * 72 + cq + 8] = *(short8*)&tmd[8];
            *(short8*)&SE[r * 72 + cq]     = *(short8*)&tme[0];
            *(short8*)&SE[r * 72 + cq + 8] = *(short8*)&tme[8];

            __builtin_amdgcn_wave_barrier();     // writes above before reads below

            const short8 a0 = afrag(SD, lane, 0);
            const short8 a1 = afrag(SD, lane, 1);
            const short8 g0 = afrag(SE, lane, 0);
            const short8 g1 = afrag(SE, lane, 1);

            #pragma unroll
            for (int hd = 0; hd < 4; ++hd) {
                f32x4 aK = {0.f, 0.f, 0.f, 0.f}, aV = aK, aR = aK;
                aK = MFMA16(a0, bK0[hd], aK); aK = MFMA16(a1, bK1[hd], aK);
                aV = MFMA16(a0, bV0[hd], aV); aV = MFMA16(a1, bV1[hd], aV);
                aR = MFMA16(g0, bR0[hd], aR); aR = MFMA16(g1, bR1[hd], aR);

                #pragma unroll
                for (int reg = 0; reg < 4; ++reg) {
                    const int rl   = (lq << 2) + reg;
                    const int eloc = rl >> 1;
                    const int n2   = reg & 1;
                    const bool valid = ((c << 3) + eloc) < deg;
                    const float kk = aK[reg];
                    const float sk = red16(kk * kk);
                    const float scale = sqrtf(sk) * (n2 ? qn1[hd] : qn0[hd]) + 1e-6f;
                    const float qv = n2 ? q1[hd] : q0[hd];
                    float msg = (qv * kk * scale + aR[reg]) * aV[reg];
                    msg = valid ? msg : NEG_INF;
                    if (n2) rm1[hd] = fmaxf(rm1[hd], msg);
                    else    rm0[hd] = fmaxf(rm0[hd], msg);
                }
            }
            __builtin_amdgcn_wave_barrier();     // reads above before next writes
        }

        #pragma unroll
        for (int hd = 0; hd < 4; ++hd) {
            rm0[hd] = fmaxf(rm0[hd], __shfl_xor(rm0[hd], 16));
            rm0[hd] = fmaxf(rm0[hd], __shfl_xor(rm0[hd], 32));
            rm1[hd] = fmaxf(rm1[hd], __shfl_xor(rm1[hd], 16));
            rm1[hd] = fmaxf(rm1[hd], __shfl_xor(rm1[hd], 32));
        }
        const float o0 = (lq == 0) ? rm0[0] : (lq == 1) ? rm0[1] : (lq == 2) ? rm0[2] : rm0[3];
        const float o1 = (lq == 0) ? rm1[0] : (lq == 1) ? rm1[1] : (lq == 2) ? rm1[2] : rm1[3];
        out[(v << 7) + lane]      = o0;
        out[(v << 7) + 64 + lane] = o1;
    }
}

// ======================= fallback path (R4, verified) =======================
__global__ __launch_bounds__(256) void zero_counts_kernel(int* __restrict__ counts) {
    const int i = blockIdx.x * 256 + threadIdx.x;
    if (i < N_NODES) counts[i] = 0;
}
__global__ __launch_bounds__(256) void hist_kernel(const int* __restrict__ dst,
                                                   int* __restrict__ counts) {
    const int i = blockIdx.x * 256 + threadIdx.x;
    if (i < N_EDGES) atomicAdd(&counts[dst[i]], 1);
}
#define BPT 98
__global__ __launch_bounds__(256) void scan_kernel(const int* __restrict__ counts,
                                                   int* __restrict__ offsets,
                                                   int* __restrict__ cursor) {
    __shared__ int part[256];
    const int t = threadIdx.x;
    const int base = t * BPT;
    int s = 0;
    for (int j = 0; j < BPT; ++j) {
        const int idx = base + j;
        if (idx < N_NODES) s += counts[idx];
    }
    part[t] = s;
    __syncthreads();
    for (int d = 1; d < 256; d <<= 1) {
        const int add = (t >= d) ? part[t - d] : 0;
        __syncthreads();
        part[t] += add;
        __syncthreads();
    }
    int run = (t > 0) ? part[t - 1] : 0;
    for (int j = 0; j < BPT; ++j) {
        const int idx = base + j;
        if (idx < N_NODES) {
            offsets[idx] = run;
            cursor[idx]  = run;
            run += counts[idx];
        }
    }
    if (t == 255) offsets[N_NODES] = part[255];
}
__global__ __launch_bounds__(256) void scatter_kernel(
    const int* __restrict__ src, const int* __restrict__ dst,
    int* __restrict__ cursor, int* __restrict__ perm, int* __restrict__ srcs) {
    const int i = blockIdx.x * 256 + threadIdx.x;
    if (i < N_EDGES) {
        const int d = dst[i];
        const int pos = atomicAdd(&cursor[d], 1);
        perm[pos] = i;
        srcs[pos] = src[i];
    }
}
__global__ __launch_bounds__(256) void q_mfma_kernel(
    const float* __restrict__ h, const float* __restrict__ Wq,
    const float* __restrict__ Wk, const float* __restrict__ Wv,
    const float* __restrict__ Wr, float* __restrict__ Q, short8* __restrict__ fw)
{
    __shared__ short sH[64 * 72];
    const int t = threadIdx.x;
    const int lane = t & 63, w = t >> 6;
    const int wcol = w << 4;
    const int ln = lane & 15, lq = lane >> 4;
    const int base = blockIdx.x * 64;
    const short8 b0 = load_bfrag(Wq, wcol, lane, 0);
    const short8 b1 = load_bfrag(Wq, wcol, lane, 1);
    {
        const int r = t >> 2, c4 = (t & 3) << 4;
        int row = base + r; if (row > 49999) row = 49999;
        const float4* p = (const float4*)&h[row * 64 + c4];
        short tmp[16];
        #pragma unroll
        for (int i = 0; i < 4; ++i) {
            float4 x = p[i];
            tmp[4*i+0] = bf16r(x.x); tmp[4*i+1] = bf16r(x.y);
            tmp[4*i+2] = bf16r(x.z); tmp[4*i+3] = bf16r(x.w);
        }
        *(short8*)&sH[r * 72 + c4]     = *(short8*)&tmp[0];
        *(short8*)&sH[r * 72 + c4 + 8] = *(short8*)&tmp[8];
    }
    __syncthreads();
    #pragma unroll
    for (int m = 0; m < 4; ++m) {
        const short* Sm = &sH[(m << 4) * 72];
        short8 a0 = afrag(Sm, lane, 0);
        short8 a1 = afrag(Sm, lane, 1);
        f32x4 acc = {0.f, 0.f, 0.f, 0.f};
        acc = MFMA16(a0, b0, acc);
        acc = MFMA16(a1, b1, acc);
        #pragma unroll
        for (int reg = 0; reg < 4; ++reg) {
            const int row = base + (m << 4) + (lq << 2) + reg;
            if (row < 50000) Q[row * 64 + wcol + ln] = acc[reg];
        }
    }
    if (blockIdx.x == 0) {
        fw[(w * 6 + 0) * 64 + lane] = load_bfrag(Wk, wcol, lane, 0);
        fw[(w * 6 + 1) * 64 + lane] = load_bfrag(Wk, wcol, lane, 1);
        fw[(w * 6 + 2) * 64 + lane] = load_bfrag(Wv, wcol, lane, 0);
        fw[(w * 6 + 3) * 64 + lane] = load_bfrag(Wv, wcol, lane, 1);
        fw[(w * 6 + 4) * 64 + lane] = load_bfrag(Wr, wcol, lane, 0);
        fw[(w * 6 + 5) * 64 + lane] = load_bfrag(Wr, wcol, lane, 1);
    }
}
__global__ __launch_bounds__(256, 2) void edge_wave_kernel(
    const float* __restrict__ h, const float* __restrict__ e,
    const float* __restrict__ Q, const int* __restrict__ srcs,
    const int* __restrict__ perm, const int* __restrict__ offsets,
    const short8* __restrict__ fw, float* __restrict__ out)
{
    __shared__ short sAll[4][2304];
    const int t = threadIdx.x;
    const int lane = t & 63, w = t >> 6;
    const int v = (blockIdx.x << 2) + w;
    short* SD = &sAll[w][0];
    short* SE = &sAll[w][1152];
    const int off0 = offsets[v];
    const int off1 = offsets[v + 1];
    const int deg  = off1 - off0;
    if (deg == 0) {
        out[(v << 7) + lane]      = 0.0f;
        out[(v << 7) + 64 + lane] = 0.0f;
        return;
    }
    const int ln = lane & 15, lq = lane >> 4;
    short8 bK0[4], bK1[4], bV0[4], bV1[4], bR0[4], bR1[4];
    #pragma unroll
    for (int hd = 0; hd < 4; ++hd) {
        bK0[hd] = fw[(hd * 6 + 0) * 64 + lane];
        bK1[hd] = fw[(hd * 6 + 1) * 64 + lane];
        bV0[hd] = fw[(hd * 6 + 2) * 64 + lane];
        bV1[hd] = fw[(hd * 6 + 3) * 64 + lane];
        bR0[hd] = fw[(hd * 6 + 4) * 64 + lane];
        bR1[hd] = fw[(hd * 6 + 5) * 64 + lane];
    }
    float q0[4], q1[4], qn0[4], qn1[4];
    #pragma unroll
    for (int hd = 0; hd < 4; ++hd) {
        q0[hd] = Q[(v << 7) + (hd << 4) + ln];
        q1[hd] = Q[(v << 7) + 64 + (hd << 4) + ln];
        qn0[hd] = sqrtf(red16(q0[hd] * q0[hd]));
        qn1[hd] = sqrtf(red16(q1[hd] * q1[hd]));
    }
    const int r = lane >> 2;
    const int cq = (lane & 3) << 4;
    const int n_r = r & 1;
    float4 xd[4];
    {
        const float4* pd = (const float4*)&h[(((v << 1) + n_r) << 6) + cq];
        xd[0] = pd[0]; xd[1] = pd[1]; xd[2] = pd[2]; xd[3] = pd[3];
    }
    const float NEG_INF = __uint_as_float(0xFF800000u);
    float rm0[4] = {NEG_INF, NEG_INF, NEG_INF, NEG_INF};
    float rm1[4] = {NEG_INF, NEG_INF, NEG_INF, NEG_INF};
    const int nch = (deg + 7) >> 3;
    for (int c = 0; c < nch; ++c) {
        int eidx = off0 + (c << 3) + (r >> 1);
        if (eidx > off1 - 1) eidx = off1 - 1;
        const int ed = perm[eidx];
        const int s  = srcs[eidx];
        const float4* ps = (const float4*)&h[(((s  << 1) + n_r) << 6) + cq];
        const float4* pe = (const float4*)&e[(((ed << 1) + n_r) << 6) + cq];
        short tmd[16], tme[16];
        #pragma unroll
        for (int i = 0; i < 4; ++i) {
            const float4 xs = ps[i], xe = pe[i];
            tmd[4*i+0] = bfr(fmaxf(xs.x - xd[i].x, 0.f));
            tmd[4*i+1] = bfr(fmaxf(xs.y - xd[i].y, 0.f));
            tmd[4*i+2] = bfr(fmaxf(xs.z - xd[i].z, 0.f));
            tmd[4*i+3] = bfr(fmaxf(xs.w - xd[i].w, 0.f));
            tme[4*i+0] = bfr(xe.x); tme[4*i+1] = bfr(xe.y);
            tme[4*i+2] = bfr(xe.z); tme[4*i+3] = bfr(xe.w);
        }
        *(short8*)&SD[r * 72 + cq]     = *(short8*)&tmd[0];
        *(short8*)&SD[r * 72 + cq + 8] = *(short8*)&tmd[8];
        *(short8*)&SE[r * 72 + cq]     = *(short8*)&tme[0];
        *(short8*)&SE[r * 72 + cq + 8] = *(short8*)&tme[8];
        __builtin_amdgcn_wave_barrier();
        const short8 a0 = afrag(SD, lane, 0);
        const short8 a1 = afrag(SD, lane, 1);
        const short8 g0 = afrag(SE, lane, 0);
        const short8 g1 = afrag(SE, lane, 1);
        #pragma unroll
        for (int hd = 0; hd < 4; ++hd) {
            f32x4 aK = {0.f, 0.f, 0.f, 0.f}, aV = aK, aR = aK;
            aK = MFMA16(a0, bK0[hd], aK); aK = MFMA16(a1, bK1[hd], aK);
            aV = MFMA16(a0, bV0[hd], aV); aV = MFMA16(a1, bV1[hd], aV);
            aR = MFMA16(g0, bR0[hd], aR); aR = MFMA16(g1, bR1[hd], aR);
            #pragma unroll
            for (int reg = 0; reg < 4; ++reg) {
                const int rl   = (lq << 2) + reg;
                const int eloc = rl >> 1;
                const int n2   = reg & 1;
                const bool valid = ((c << 3) + eloc) < deg;
                const float kk = aK[reg];
                const float sk = red16(kk * kk);
                const float scale = sqrtf(sk) * (n2 ? qn1[hd] : qn0[hd]) + 1e-6f;
                const float qv = n2 ? q1[hd] : q0[hd];
                float msg = (qv * kk * scale + aR[reg]) * aV[reg];
                msg = valid ? msg : NEG_INF;
                if (n2) rm1[hd] = fmaxf(rm1[hd], msg);
                else    rm0[hd] = fmaxf(rm0[hd], msg);
            }
        }
        __builtin_amdgcn_wave_barrier();
    }
    #pragma unroll
    for (int hd = 0; hd < 4; ++hd) {
        rm0[hd] = fmaxf(rm0[hd], __shfl_xor(rm0[hd], 16));
        rm0[hd] = fmaxf(rm0[hd], __shfl_xor(rm0[hd], 32));
        rm1[hd] = fmaxf(rm1[hd], __shfl_xor(rm1[hd], 16));
        rm1[hd] = fmaxf(rm1[hd], __shfl_xor(rm1[hd], 32));
    }
    const float o0 = (lq == 0) ? rm0[0] : (lq == 1) ? rm0[1] : (lq == 2) ? rm0[2] : rm0[3];
    const float o1 = (lq == 0) ? rm1[0] : (lq == 1) ? rm1[1] : (lq == 2) ? rm1[2] : rm1[3];
    out[(v << 7) + lane]      = o0;
    out[(v << 7) + 64 + lane] = o1;
}

extern "C" void kernel_launch(void* const* d_in, const int* in_sizes, int n_in,
                              void* d_out, int out_size, void* d_ws, size_t ws_size,
                              hipStream_t stream) {
    const float* h  = (const float*)d_in[0];
    const float* e  = (const float*)d_in[1];
    const float* Wq = (const float*)d_in[2];
    const float* Wk = (const float*)d_in[3];
    const float* Wv = (const float*)d_in[4];
    const float* Wr = (const float*)d_in[5];
    const int*   src = (const int*)d_in[6];
    const int*   dst = (const int*)d_in[7];
    float* out = (float*)d_out;

    // workspace layout (4B units), ~16.34 MB
    float*  Q        = (float*)d_ws;                     // 3,200,000
    int*    counts   = (int*)d_ws + 3200000;             // 25,000
    int*    offsets  = (int*)d_ws + 3225000;             // 25,001
    int*    cursor   = (int*)d_ws + 3250008;             // 25,000
    int*    perm     = (int*)d_ws + 3275008;             // 400,000
    int*    srcs     = (int*)d_ws + 3675008;             // 400,000
    short8* fw       = (short8*)((int*)d_ws + 4075008);  // 1536 x 16B (16B-aligned)
    int*    partials = (int*)d_ws + 4081152;             // up to 2,048

    // deterministic grid sizing for cooperative launch
    int maxB = 0;
    hipError_t qerr = hipOccupancyMaxActiveBlocksPerMultiprocessor(
        &maxB, reinterpret_cast<const void*>(fused_kernel), 256, 0);
    int G = (qerr == hipSuccess && maxB > 0) ? maxB * 256 : 0;
    if (G > 2048) G = 2048;

    hipError_t err = hipErrorUnknown;
    if (G >= 98) {   // scan design requires C<=256
        void* args[] = {
            (void*)&h, (void*)&e, (void*)&Wq, (void*)&Wk, (void*)&Wv, (void*)&Wr,
            (void*)&src, (void*)&dst, (void*)&Q, (void*)&counts, (void*)&offsets,
            (void*)&cursor, (void*)&perm, (void*)&srcs, (void*)&fw,
            (void*)&partials, (void*)&out
        };
        err = hipLaunchCooperativeKernel(reinterpret_cast<const void*>(fused_kernel),
                                         dim3(G), dim3(256), args, 0, stream);
    }
    if (err != hipSuccess) {   // fallback: verified R4 multi-kernel path
        zero_counts_kernel<<<98, 256, 0, stream>>>(counts);
        hist_kernel<<<1563, 256, 0, stream>>>(dst, counts);
        scan_kernel<<<1, 256, 0, stream>>>(counts, offsets, cursor);
        scatter_kernel<<<1563, 256, 0, stream>>>(src, dst, cursor, perm, srcs);
        q_mfma_kernel<<<782, 256, 0, stream>>>(h, Wq, Wk, Wv, Wr, Q, fw);
        edge_wave_kernel<<<6250, 256, 0, stream>>>(h, e, Q, srcs, perm, offsets, fw, out);
    }
}